// Round 11
// baseline (179.363 us; speedup 1.0000x reference)
//
#include <hip/hip_runtime.h>
#include <math.h>
#include <stdint.h>

#define B_ 8
#define T_ 256
#define N_ 128
#define K_ 64
#define NCH 32
#define LOG128 4.852030263919617f
#define STRIDE_S 4128   // padded 16-col-block / strip stride in bytes

typedef __attribute__((ext_vector_type(2))) unsigned int u32x2;
typedef __attribute__((ext_vector_type(4))) unsigned int u32x4;
typedef __attribute__((ext_vector_type(4))) float f32x4;
typedef __attribute__((ext_vector_type(8))) short short8;

__device__ __forceinline__ uint32_t cvtpk(float lo, float hi) {
    uint32_t r;
    asm("v_cvt_pk_bf16_f32 %0, %1, %2" : "=v"(r) : "v"(lo), "v"(hi));
    return r;
}
__device__ __forceinline__ float blo(uint32_t w) { return __uint_as_float(w << 16); }
__device__ __forceinline__ float bhi(uint32_t w) { return __uint_as_float(w & 0xffff0000u); }

#define TRRD(dst, addr) asm volatile("ds_read_b64_tr_b16 %0, %1" : "=v"(dst) : "v"(addr) : "memory")
// lgkmcnt is a 4-bit field: counts must be <= 15
#define WAITL8  { asm volatile("s_waitcnt lgkmcnt(8)"  ::: "memory"); __builtin_amdgcn_sched_barrier(0); }
#define WAITL0  { asm volatile("s_waitcnt lgkmcnt(0)"  ::: "memory"); __builtin_amdgcn_sched_barrier(0); }
// Barrier with LDS-only drain: keeps global prefetch loads in flight across it.
#define BARRIER_LG() { asm volatile("s_waitcnt lgkmcnt(0)" ::: "memory"); \
                       __builtin_amdgcn_s_barrier(); \
                       __builtin_amdgcn_sched_barrier(0); }

// ---------------- Kernel 1: emission probabilities (softmax of obs @ W + b) ----------------
__global__ __launch_bounds__(128) void k_emit(
    const float* __restrict__ obs,    // [B,T,K]
    const int*   __restrict__ dur,    // [B]
    const float* __restrict__ W,      // [K,N]
    const float* __restrict__ bias,   // [N]
    float* __restrict__ e)            // [B,T,N] softmax probs
{
    int bt = blockIdx.x;
    int b  = bt >> 8;
    int t  = bt & 255;
    if (t >= dur[b]) return;
    int n = threadIdx.x;
    __shared__ float o[K_];
    __shared__ float wmax[2];
    __shared__ float wsum[2];
    if (n < K_) o[n] = obs[(size_t)bt * K_ + n];
    __syncthreads();
    float acc = bias[n];
    #pragma unroll
    for (int k = 0; k < K_; ++k)
        acc = fmaf(o[k], W[k * N_ + n], acc);
    float m = acc;
    #pragma unroll
    for (int off = 32; off; off >>= 1) m = fmaxf(m, __shfl_xor(m, off));
    int w = n >> 6;
    if ((n & 63) == 0) wmax[w] = m;
    __syncthreads();
    float M = fmaxf(wmax[0], wmax[1]);
    float ex = expf(acc - M);
    float s = ex;
    #pragma unroll
    for (int off = 32; off; off >>= 1) s += __shfl_xor(s, off);
    if ((n & 63) == 0) wsum[w] = s;
    __syncthreads();
    float S = wsum[0] + wsum[1];
    e[(size_t)bt * N_ + n] = ex / S;
}

// ---------------- Kernel 2: chunk matrix products via MFMA (identical to round 10) ----------------
__global__ __launch_bounds__(512, 1) void k_chunk(
    const float* __restrict__ trans,  // [T,B,N,N]
    const int*   __restrict__ dur,
    const float* __restrict__ e,      // [B,T,N]
    uint32_t* __restrict__ gout)      // [B][NCH][8192] u32
{
    const int bc = blockIdx.x;
    const int b  = bc & 7;
    const int c  = bc >> 3;
    const int d  = dur[b];
    const int t0 = c * 8 + 1;
    if (t0 > d - 1) return;
    int te = c * 8 + 8; if (te > d - 1) te = d - 1;

    const int tid  = threadIdx.x;
    const int lane = tid & 63;
    const int wv   = tid >> 6;
    const int cc   = lane & 15;
    const int gq   = lane >> 4;

    __shared__ __align__(16) uint8_t ldsC[2][8 * STRIDE_S];
    __shared__ __align__(16) uint8_t strips[8 * STRIDE_S];

    {
        uint32_t* sw = (uint32_t*)(strips + wv * STRIDE_S);
        #pragma unroll
        for (int i = 0; i < 16; ++i) sw[lane + i * 64] = 0;
        if (lane < 16)
            ((uint16_t*)(strips + wv * STRIDE_S))[(16 * wv + lane) * 16 + lane] = 0x3F80u;
    }

    const uint32_t sbase = (uint32_t)(uintptr_t)&strips[wv * STRIDE_S];
    const uint32_t lt    = (uint32_t)(cc * 2 + gq * 256);
    const int row0 = tid >> 5;
    const int jbp  = (tid & 31) >> 2;
    const int cc0  = (tid & 3) << 2;

    float4 vA[8], vB[8];
    float  eA[8], eB[8];
    {
        const float4* gp = (const float4*)(trans + (((size_t)t0 * B_ + b) << 14));
        #pragma unroll
        for (int i = 0; i < 8; ++i) vA[i] = gp[tid + i * 512];
        #pragma unroll
        for (int i = 0; i < 8; ++i)
            eA[i] = e[((size_t)b * T_ + (t0 - 1)) * N_ + row0 + i * 16];
    }
    if (t0 + 1 <= te) {
        const float4* gp = (const float4*)(trans + (((size_t)(t0 + 1) * B_ + b) << 14));
        #pragma unroll
        for (int i = 0; i < 8; ++i) vB[i] = gp[tid + i * 512];
        #pragma unroll
        for (int i = 0; i < 8; ++i)
            eB[i] = e[((size_t)b * T_ + t0) * N_ + row0 + i * 16];
    }

    int buf = 0;

#define ISSUE_B(S, JB) { \
        _Pragma("unroll") \
        for (int kb = 0; kb < 4; ++kb) { \
            uint32_t bd = cbase + (uint32_t)((JB) * STRIDE_S + kb * 1024) + lt; \
            TRRD(rb[S][2 * kb],     bd); \
            TRRD(rb[S][2 * kb + 1], bd + 128); } }
#define MFMA_JB(JB, S) { \
        f32x4 d4 = (f32x4){0.f, 0.f, 0.f, 0.f}; \
        _Pragma("unroll") \
        for (int kb = 0; kb < 4; ++kb) { \
            u32x4 tmp = (u32x4){rb[S][2 * kb].x, rb[S][2 * kb].y, rb[S][2 * kb + 1].x, rb[S][2 * kb + 1].y}; \
            short8 Bf = __builtin_bit_cast(short8, tmp); \
            d4 = __builtin_amdgcn_mfma_f32_16x16x32_bf16(A[kb], Bf, d4, 0, 0, 0); } \
        acc[JB] = d4; }

#define STEP(VC, EC) { \
    uint8_t* cb = ldsC[buf]; \
    const uint32_t cbase = (uint32_t)(uintptr_t)cb; \
    _Pragma("unroll") \
    for (int i = 0; i < 8; ++i) { \
        float ps = (VC[i].x + VC[i].y) + (VC[i].z + VC[i].w); \
        ps += __shfl_xor(ps, 1); \
        ps += __shfl_xor(ps, 2); \
        ps += __shfl_xor(ps, 4); \
        ps += __shfl_xor(ps, 8); \
        ps += __shfl_xor(ps, 16); \
        float sc = 128.0f * EC[i] * __builtin_amdgcn_rcpf(ps); \
        uint32_t p0 = cvtpk(VC[i].x * sc, VC[i].y * sc); \
        uint32_t p1 = cvtpk(VC[i].z * sc, VC[i].w * sc); \
        *(uint2*)(cb + jbp * STRIDE_S + (row0 + i * 16) * 32 + cc0 * 2) = make_uint2(p0, p1); \
    } \
    if (t + 2 <= te) { \
        const float4* gp = (const float4*)(trans + (((size_t)(t + 2) * B_ + b) << 14)); \
        _Pragma("unroll") \
        for (int i = 0; i < 8; ++i) VC[i] = gp[tid + i * 512]; \
        _Pragma("unroll") \
        for (int i = 0; i < 8; ++i) \
            EC[i] = e[((size_t)b * T_ + (t + 1)) * N_ + row0 + i * 16]; \
    } \
    BARRIER_LG(); \
    { \
        u32x2 ra[8]; \
        _Pragma("unroll") \
        for (int kb = 0; kb < 4; ++kb) { \
            uint32_t ad = sbase + (uint32_t)(kb * 1024) + lt; \
            TRRD(ra[2 * kb],     ad); \
            TRRD(ra[2 * kb + 1], ad + 128); \
        } \
        u32x2 rb[2][8]; \
        f32x4 acc[8]; \
        ISSUE_B(0, 0); \
        ISSUE_B(1, 1); \
        WAITL8; \
        short8 A[4]; \
        _Pragma("unroll") \
        for (int kb = 0; kb < 4; ++kb) { \
            u32x4 tmp = (u32x4){ra[2 * kb].x, ra[2 * kb].y, ra[2 * kb + 1].x, ra[2 * kb + 1].y}; \
            A[kb] = __builtin_bit_cast(short8, tmp); \
        } \
        MFMA_JB(0, 0); \
        ISSUE_B(0, 2); WAITL8; MFMA_JB(1, 1); \
        ISSUE_B(1, 3); WAITL8; MFMA_JB(2, 0); \
        ISSUE_B(0, 4); WAITL8; MFMA_JB(3, 1); \
        ISSUE_B(1, 5); WAITL8; MFMA_JB(4, 0); \
        ISSUE_B(0, 6); WAITL8; MFMA_JB(5, 1); \
        ISSUE_B(1, 7); WAITL8; MFMA_JB(6, 0); \
        WAITL0;                MFMA_JB(7, 1); \
        _Pragma("unroll") \
        for (int jb = 0; jb < 8; ++jb) { \
            uint32_t p0 = cvtpk(acc[jb][0], acc[jb][1]); \
            uint32_t p1 = cvtpk(acc[jb][2], acc[jb][3]); \
            *(uint2*)(strips + wv * STRIDE_S + (jb * 16 + cc) * 32 + gq * 8) = make_uint2(p0, p1); \
        } \
    } \
    buf ^= 1; \
}

    int t = t0;
    while (true) {
        STEP(vA, eA); ++t; if (t > te) break;
        STEP(vB, eB); ++t; if (t > te) break;
    }
#undef STEP
#undef ISSUE_B
#undef MFMA_JB

    uint32_t* gdst = gout + ((size_t)(b * NCH + c) << 13);
    #pragma unroll
    for (int kb = 0; kb < 4; ++kb) {
        u32x2 e0, e1;
        uint32_t ad = sbase + (uint32_t)(kb * 1024) + lt;
        TRRD(e0, ad);
        TRRD(e1, ad + 128);
        WAITL0;
        u32x4 o = (u32x4){e0.x, e0.y, e1.x, e1.y};
        *(u32x4*)(gdst + (size_t)((16 * wv + cc) * 64 + kb * 16 + gq * 4)) = o;
    }
}

// ---------------- Kernel 3: serial combine (identical to round 10) ----------------
__global__ __launch_bounds__(256, 1) void k_comb(
    const uint32_t* __restrict__ gtiles, // [B][NCH][8192] u32, G row-major bf16
    const int*   __restrict__ dur,
    const float* __restrict__ sp,        // [B,N]
    const float* __restrict__ e,         // [B,T,N]
    float* __restrict__ out)             // [B]
{
    const int b   = blockIdx.x;
    const int tid = threadIdx.x;
    const int wv  = tid >> 6;
    const int l   = tid & 63;
    const int d   = dur[b];
    const int nc  = (d - 1 + 7) >> 3;

    __shared__ float  gl[2][N_];
    __shared__ float2 part[2][4][64];

    float g0 = sp[b * N_ + 2 * l];
    float g1 = sp[b * N_ + 2 * l + 1];
    float S  = -(float)(d - 1) * LOG128;
    *(float2*)&gl[0][2 * l] = make_float2(g0, g1);

    const uint32_t* gb = gtiles + (((size_t)b * NCH) << 13) + l;
    uint32_t cwA[32], cwB[32], cwC[32], cwD[32];
    int p = 0;

#define LOADCH(P, C) { \
    const uint32_t* gp_ = gb + ((size_t)(C) << 13); \
    _Pragma("unroll") \
    for (int kk = 0; kk < 32; ++kk) P[kk] = gp_[(size_t)(wv * 32 + kk) * 64]; }

#define CSTEP(CUR, NXT, CIDX) { \
    if ((CIDX) + 3 < nc) LOADCH(NXT, (CIDX) + 3); \
    float n0a = 0.f, n0b = 0.f, n1a = 0.f, n1b = 0.f; \
    _Pragma("unroll") \
    for (int kk = 0; kk < 32; kk += 2) { \
        float gk0 = gl[p][wv * 32 + kk]; \
        float gk1 = gl[p][wv * 32 + kk + 1]; \
        n0a = fmaf(blo(CUR[kk]),     gk0, n0a); \
        n1a = fmaf(bhi(CUR[kk]),     gk0, n1a); \
        n0b = fmaf(blo(CUR[kk + 1]), gk1, n0b); \
        n1b = fmaf(bhi(CUR[kk + 1]), gk1, n1b); } \
    part[p][wv][l] = make_float2(n0a + n0b, n1a + n1b); \
    BARRIER_LG(); \
    float2 q0 = part[p][0][l], q1 = part[p][1][l], q2 = part[p][2][l], q3 = part[p][3][l]; \
    float s0 = (q0.x + q1.x) + (q2.x + q3.x); \
    float s1 = (q0.y + q1.y) + (q2.y + q3.y); \
    float mx = fmaxf(s0, s1); \
    _Pragma("unroll") \
    for (int of = 1; of < 64; of <<= 1) mx = fmaxf(mx, __shfl_xor(mx, of)); \
    float mr = __builtin_amdgcn_rcpf(mx); \
    g0 = s0 * mr; g1 = s1 * mr; \
    S -= __logf(mr); \
    *(float2*)&gl[p ^ 1][2 * l] = make_float2(g0, g1); \
    p ^= 1; \
}

    if (nc > 0) {
        LOADCH(cwA, 0);
        if (nc > 1) LOADCH(cwB, 1);
        if (nc > 2) LOADCH(cwC, 2);
        int c = 0;
        while (true) {
            CSTEP(cwA, cwD, c); ++c; if (c >= nc) break;
            CSTEP(cwB, cwA, c); ++c; if (c >= nc) break;
            CSTEP(cwC, cwB, c); ++c; if (c >= nc) break;
            CSTEP(cwD, cwC, c); ++c; if (c >= nc) break;
        }
    }
#undef LOADCH
#undef CSTEP

    float e0 = e[((size_t)b * T_ + (d - 1)) * N_ + 2 * l];
    float e1 = e[((size_t)b * T_ + (d - 1)) * N_ + 2 * l + 1];
    float sv = g0 * e0 + g1 * e1;
    #pragma unroll
    for (int of = 1; of < 64; of <<= 1) sv += __shfl_xor(sv, of);
    if (tid == 0) out[b] = S + logf(sv);
}

extern "C" void kernel_launch(void* const* d_in, const int* in_sizes, int n_in,
                              void* d_out, int out_size, void* d_ws, size_t ws_size,
                              hipStream_t stream) {
    const float* obs   = (const float*)d_in[0];   // [B,T,K]
    const int*   dur   = (const int*)  d_in[1];   // [B]
    const float* trans = (const float*)d_in[2];   // [T,B,N,N]
    const float* sp    = (const float*)d_in[3];   // [B,N]
    const float* W     = (const float*)d_in[4];   // [K,N]
    const float* bias  = (const float*)d_in[5];   // [N]
    float* out = (float*)d_out;

    const size_t MB = 1u << 20;
    float*    e    = (float*)d_ws;                               // 1 MB
    uint32_t* gout = (uint32_t*)((char*)d_ws + 1 * MB);          // 8 MB
    float*    oscr = (float*)((char*)d_ws + 9 * MB);             // replica outputs (scratch)

    hipLaunchKernelGGL(k_emit,  dim3(B_ * T_),  dim3(128), 0, stream, obs, dur, W, bias, e);
    hipLaunchKernelGGL(k_chunk, dim3(B_ * NCH), dim3(512), 0, stream, trans, dur, e, gout);
    // === MEASUREMENT: 4 idempotent replicas of k_comb -> scratch ===
    // dur_new - dur_r10 = 4*comb + 4*launch_overhead  (kernels byte-identical to r10)
    hipLaunchKernelGGL(k_comb,  dim3(B_),       dim3(256), 0, stream, gout, dur, sp, e, oscr + 0);
    hipLaunchKernelGGL(k_comb,  dim3(B_),       dim3(256), 0, stream, gout, dur, sp, e, oscr + 1024);
    hipLaunchKernelGGL(k_comb,  dim3(B_),       dim3(256), 0, stream, gout, dur, sp, e, oscr + 2048);
    hipLaunchKernelGGL(k_comb,  dim3(B_),       dim3(256), 0, stream, gout, dur, sp, e, oscr + 3072);
    // the real one:
    hipLaunchKernelGGL(k_comb,  dim3(B_),       dim3(256), 0, stream, gout, dur, sp, e, out);
}

// Round 12
// 62.558 us; speedup vs baseline: 2.8671x; 2.8671x over previous
//
#include <hip/hip_runtime.h>
#include <math.h>
#include <stdint.h>

#define B_ 8
#define T_ 256
#define N_ 128
#define K_ 64
#define NCH 32
#define LOG128 4.852030263919617f
#define STRIDE_S 4128   // padded 16-col-block / strip stride in bytes

typedef __attribute__((ext_vector_type(2))) unsigned int u32x2;
typedef __attribute__((ext_vector_type(4))) unsigned int u32x4;
typedef __attribute__((ext_vector_type(4))) float f32x4;
typedef __attribute__((ext_vector_type(8))) short short8;

__device__ __forceinline__ uint32_t cvtpk(float lo, float hi) {
    uint32_t r;
    asm("v_cvt_pk_bf16_f32 %0, %1, %2" : "=v"(r) : "v"(lo), "v"(hi));
    return r;
}
__device__ __forceinline__ float blo(uint32_t w) { return __uint_as_float(w << 16); }
__device__ __forceinline__ float bhi(uint32_t w) { return __uint_as_float(w & 0xffff0000u); }

#define TRRD(dst, addr) asm volatile("ds_read_b64_tr_b16 %0, %1" : "=v"(dst) : "v"(addr) : "memory")
// lgkmcnt is a 4-bit field: counts must be <= 15
#define WAITL8  { asm volatile("s_waitcnt lgkmcnt(8)"  ::: "memory"); __builtin_amdgcn_sched_barrier(0); }
#define WAITL0  { asm volatile("s_waitcnt lgkmcnt(0)"  ::: "memory"); __builtin_amdgcn_sched_barrier(0); }
// Barrier with LDS-only drain: keeps global prefetch loads in flight across it.
#define BARRIER_LG() { asm volatile("s_waitcnt lgkmcnt(0)" ::: "memory"); \
                       __builtin_amdgcn_s_barrier(); \
                       __builtin_amdgcn_sched_barrier(0); }

// VALU-only wave64 max (DPP + readlane): no LDS-pipe ops, nothing for lgkmcnt
// to drain. Requirement is only UNIFORMITY (readlane) + positivity (guarded):
// the rescale algorithm is exact for any applied factor since S -= log(mr).
__device__ __forceinline__ float wave_max_dpp(float x) {
    int v = __float_as_int(x);
    int t;
    t = __builtin_amdgcn_update_dpp(0, v, 0x111, 0xf, 0xf, true); // row_shr:1
    v = __float_as_int(fmaxf(__int_as_float(v), __int_as_float(t)));
    t = __builtin_amdgcn_update_dpp(0, v, 0x112, 0xf, 0xf, true); // row_shr:2
    v = __float_as_int(fmaxf(__int_as_float(v), __int_as_float(t)));
    t = __builtin_amdgcn_update_dpp(0, v, 0x114, 0xf, 0xf, true); // row_shr:4
    v = __float_as_int(fmaxf(__int_as_float(v), __int_as_float(t)));
    t = __builtin_amdgcn_update_dpp(0, v, 0x118, 0xf, 0xf, true); // row_shr:8
    v = __float_as_int(fmaxf(__int_as_float(v), __int_as_float(t)));
    t = __builtin_amdgcn_update_dpp(0, v, 0x142, 0xa, 0xf, true); // row_bcast:15
    v = __float_as_int(fmaxf(__int_as_float(v), __int_as_float(t)));
    t = __builtin_amdgcn_update_dpp(0, v, 0x143, 0xc, 0xf, true); // row_bcast:31
    v = __float_as_int(fmaxf(__int_as_float(v), __int_as_float(t)));
    return __int_as_float(__builtin_amdgcn_readlane(v, 63));
}

// ---------------- Kernel 1: emission probabilities (softmax of obs @ W + b) ----------------
__global__ __launch_bounds__(128) void k_emit(
    const float* __restrict__ obs,    // [B,T,K]
    const int*   __restrict__ dur,    // [B]
    const float* __restrict__ W,      // [K,N]
    const float* __restrict__ bias,   // [N]
    float* __restrict__ e)            // [B,T,N] softmax probs
{
    int bt = blockIdx.x;
    int b  = bt >> 8;
    int t  = bt & 255;
    if (t >= dur[b]) return;
    int n = threadIdx.x;
    __shared__ float o[K_];
    __shared__ float wmax[2];
    __shared__ float wsum[2];
    if (n < K_) o[n] = obs[(size_t)bt * K_ + n];
    __syncthreads();
    float acc = bias[n];
    #pragma unroll
    for (int k = 0; k < K_; ++k)
        acc = fmaf(o[k], W[k * N_ + n], acc);
    float m = acc;
    #pragma unroll
    for (int off = 32; off; off >>= 1) m = fmaxf(m, __shfl_xor(m, off));
    int w = n >> 6;
    if ((n & 63) == 0) wmax[w] = m;
    __syncthreads();
    float M = fmaxf(wmax[0], wmax[1]);
    float ex = expf(acc - M);
    float s = ex;
    #pragma unroll
    for (int off = 32; off; off >>= 1) s += __shfl_xor(s, off);
    if ((n & 63) == 0) wsum[w] = s;
    __syncthreads();
    float S = wsum[0] + wsum[1];
    e[(size_t)bt * N_ + n] = ex / S;
}

// ---------------- Kernel 2: chunk matrix products via MFMA (identical to round 10) ----------------
__global__ __launch_bounds__(512, 1) void k_chunk(
    const float* __restrict__ trans,  // [T,B,N,N]
    const int*   __restrict__ dur,
    const float* __restrict__ e,      // [B,T,N]
    uint32_t* __restrict__ gout)      // [B][NCH][8192] u32
{
    const int bc = blockIdx.x;
    const int b  = bc & 7;
    const int c  = bc >> 3;
    const int d  = dur[b];
    const int t0 = c * 8 + 1;
    if (t0 > d - 1) return;
    int te = c * 8 + 8; if (te > d - 1) te = d - 1;

    const int tid  = threadIdx.x;
    const int lane = tid & 63;
    const int wv   = tid >> 6;
    const int cc   = lane & 15;
    const int gq   = lane >> 4;

    __shared__ __align__(16) uint8_t ldsC[2][8 * STRIDE_S];
    __shared__ __align__(16) uint8_t strips[8 * STRIDE_S];

    {
        uint32_t* sw = (uint32_t*)(strips + wv * STRIDE_S);
        #pragma unroll
        for (int i = 0; i < 16; ++i) sw[lane + i * 64] = 0;
        if (lane < 16)
            ((uint16_t*)(strips + wv * STRIDE_S))[(16 * wv + lane) * 16 + lane] = 0x3F80u;
    }

    const uint32_t sbase = (uint32_t)(uintptr_t)&strips[wv * STRIDE_S];
    const uint32_t lt    = (uint32_t)(cc * 2 + gq * 256);
    const int row0 = tid >> 5;
    const int jbp  = (tid & 31) >> 2;
    const int cc0  = (tid & 3) << 2;

    float4 vA[8], vB[8];
    float  eA[8], eB[8];
    {
        const float4* gp = (const float4*)(trans + (((size_t)t0 * B_ + b) << 14));
        #pragma unroll
        for (int i = 0; i < 8; ++i) vA[i] = gp[tid + i * 512];
        #pragma unroll
        for (int i = 0; i < 8; ++i)
            eA[i] = e[((size_t)b * T_ + (t0 - 1)) * N_ + row0 + i * 16];
    }
    if (t0 + 1 <= te) {
        const float4* gp = (const float4*)(trans + (((size_t)(t0 + 1) * B_ + b) << 14));
        #pragma unroll
        for (int i = 0; i < 8; ++i) vB[i] = gp[tid + i * 512];
        #pragma unroll
        for (int i = 0; i < 8; ++i)
            eB[i] = e[((size_t)b * T_ + t0) * N_ + row0 + i * 16];
    }

    int buf = 0;

#define ISSUE_B(S, JB) { \
        _Pragma("unroll") \
        for (int kb = 0; kb < 4; ++kb) { \
            uint32_t bd = cbase + (uint32_t)((JB) * STRIDE_S + kb * 1024) + lt; \
            TRRD(rb[S][2 * kb],     bd); \
            TRRD(rb[S][2 * kb + 1], bd + 128); } }
#define MFMA_JB(JB, S) { \
        f32x4 d4 = (f32x4){0.f, 0.f, 0.f, 0.f}; \
        _Pragma("unroll") \
        for (int kb = 0; kb < 4; ++kb) { \
            u32x4 tmp = (u32x4){rb[S][2 * kb].x, rb[S][2 * kb].y, rb[S][2 * kb + 1].x, rb[S][2 * kb + 1].y}; \
            short8 Bf = __builtin_bit_cast(short8, tmp); \
            d4 = __builtin_amdgcn_mfma_f32_16x16x32_bf16(A[kb], Bf, d4, 0, 0, 0); } \
        acc[JB] = d4; }

#define STEP(VC, EC) { \
    uint8_t* cb = ldsC[buf]; \
    const uint32_t cbase = (uint32_t)(uintptr_t)cb; \
    _Pragma("unroll") \
    for (int i = 0; i < 8; ++i) { \
        float ps = (VC[i].x + VC[i].y) + (VC[i].z + VC[i].w); \
        ps += __shfl_xor(ps, 1); \
        ps += __shfl_xor(ps, 2); \
        ps += __shfl_xor(ps, 4); \
        ps += __shfl_xor(ps, 8); \
        ps += __shfl_xor(ps, 16); \
        float sc = 128.0f * EC[i] * __builtin_amdgcn_rcpf(ps); \
        uint32_t p0 = cvtpk(VC[i].x * sc, VC[i].y * sc); \
        uint32_t p1 = cvtpk(VC[i].z * sc, VC[i].w * sc); \
        *(uint2*)(cb + jbp * STRIDE_S + (row0 + i * 16) * 32 + cc0 * 2) = make_uint2(p0, p1); \
    } \
    if (t + 2 <= te) { \
        const float4* gp = (const float4*)(trans + (((size_t)(t + 2) * B_ + b) << 14)); \
        _Pragma("unroll") \
        for (int i = 0; i < 8; ++i) VC[i] = gp[tid + i * 512]; \
        _Pragma("unroll") \
        for (int i = 0; i < 8; ++i) \
            EC[i] = e[((size_t)b * T_ + (t + 1)) * N_ + row0 + i * 16]; \
    } \
    BARRIER_LG(); \
    { \
        u32x2 ra[8]; \
        _Pragma("unroll") \
        for (int kb = 0; kb < 4; ++kb) { \
            uint32_t ad = sbase + (uint32_t)(kb * 1024) + lt; \
            TRRD(ra[2 * kb],     ad); \
            TRRD(ra[2 * kb + 1], ad + 128); \
        } \
        u32x2 rb[2][8]; \
        f32x4 acc[8]; \
        ISSUE_B(0, 0); \
        ISSUE_B(1, 1); \
        WAITL8; \
        short8 A[4]; \
        _Pragma("unroll") \
        for (int kb = 0; kb < 4; ++kb) { \
            u32x4 tmp = (u32x4){ra[2 * kb].x, ra[2 * kb].y, ra[2 * kb + 1].x, ra[2 * kb + 1].y}; \
            A[kb] = __builtin_bit_cast(short8, tmp); \
        } \
        MFMA_JB(0, 0); \
        ISSUE_B(0, 2); WAITL8; MFMA_JB(1, 1); \
        ISSUE_B(1, 3); WAITL8; MFMA_JB(2, 0); \
        ISSUE_B(0, 4); WAITL8; MFMA_JB(3, 1); \
        ISSUE_B(1, 5); WAITL8; MFMA_JB(4, 0); \
        ISSUE_B(0, 6); WAITL8; MFMA_JB(5, 1); \
        ISSUE_B(1, 7); WAITL8; MFMA_JB(6, 0); \
        WAITL0;                MFMA_JB(7, 1); \
        _Pragma("unroll") \
        for (int jb = 0; jb < 8; ++jb) { \
            uint32_t p0 = cvtpk(acc[jb][0], acc[jb][1]); \
            uint32_t p1 = cvtpk(acc[jb][2], acc[jb][3]); \
            *(uint2*)(strips + wv * STRIDE_S + (jb * 16 + cc) * 32 + gq * 8) = make_uint2(p0, p1); \
        } \
    } \
    buf ^= 1; \
}

    int t = t0;
    while (true) {
        STEP(vA, eA); ++t; if (t > te) break;
        STEP(vB, eB); ++t; if (t > te) break;
    }
#undef STEP
#undef ISSUE_B
#undef MFMA_JB

    uint32_t* gdst = gout + ((size_t)(b * NCH + c) << 13);
    #pragma unroll
    for (int kb = 0; kb < 4; ++kb) {
        u32x2 e0, e1;
        uint32_t ad = sbase + (uint32_t)(kb * 1024) + lt;
        TRRD(e0, ad);
        TRRD(e1, ad + 128);
        WAITL0;
        u32x4 o = (u32x4){e0.x, e0.y, e1.x, e1.y};
        *(u32x4*)(gdst + (size_t)((16 * wv + cc) * 64 + kb * 16 + gq * 4)) = o;
    }
}

// ---------------- Kernel 3: serial combine, 4 waves per batch (k-split) ----------------
// gamma <- gamma @ G_c with LAGGED rescale: mr kicked at even chunks via a
// VALU-only DPP max (off the critical path, no lgkm ops), applied 2 chunks
// later. Exact for any uniform mr: S -= log(applied mr).
__global__ __launch_bounds__(256, 1) void k_comb(
    const uint32_t* __restrict__ gtiles, // [B][NCH][8192] u32, G row-major bf16
    const int*   __restrict__ dur,
    const float* __restrict__ sp,        // [B,N]
    const float* __restrict__ e,         // [B,T,N]
    float* __restrict__ out)             // [B]
{
    const int b   = blockIdx.x;
    const int tid = threadIdx.x;
    const int wv  = tid >> 6;
    const int l   = tid & 63;
    const int d   = dur[b];
    const int nc  = (d - 1 + 7) >> 3;

    __shared__ float  gl[2][N_];
    __shared__ float2 part[2][4][64];

    float g0 = sp[b * N_ + 2 * l];
    float g1 = sp[b * N_ + 2 * l + 1];
    float S  = -(float)(d - 1) * LOG128;
    float mrApply = 1.0f;
    *(float2*)&gl[0][2 * l] = make_float2(g0, g1);

    const uint32_t* gb = gtiles + (((size_t)b * NCH) << 13) + l;
    uint32_t cwA[32], cwB[32], cwC[32], cwD[32];
    int p = 0;

#define LOADCH(P, C) { \
    const uint32_t* gp_ = gb + ((size_t)(C) << 13); \
    _Pragma("unroll") \
    for (int kk = 0; kk < 32; ++kk) P[kk] = gp_[(size_t)(wv * 32 + kk) * 64]; }

#define CSTEP(CUR, NXT, CIDX) { \
    if ((CIDX) + 3 < nc) LOADCH(NXT, (CIDX) + 3); \
    float n0a = 0.f, n0b = 0.f, n0c = 0.f, n0d = 0.f; \
    float n1a = 0.f, n1b = 0.f, n1c = 0.f, n1d = 0.f; \
    _Pragma("unroll") \
    for (int kk = 0; kk < 32; kk += 4) { \
        float gk0 = gl[p][wv * 32 + kk]; \
        float gk1 = gl[p][wv * 32 + kk + 1]; \
        float gk2 = gl[p][wv * 32 + kk + 2]; \
        float gk3 = gl[p][wv * 32 + kk + 3]; \
        n0a = fmaf(blo(CUR[kk]),     gk0, n0a); n1a = fmaf(bhi(CUR[kk]),     gk0, n1a); \
        n0b = fmaf(blo(CUR[kk + 1]), gk1, n0b); n1b = fmaf(bhi(CUR[kk + 1]), gk1, n1b); \
        n0c = fmaf(blo(CUR[kk + 2]), gk2, n0c); n1c = fmaf(bhi(CUR[kk + 2]), gk2, n1c); \
        n0d = fmaf(blo(CUR[kk + 3]), gk3, n0d); n1d = fmaf(bhi(CUR[kk + 3]), gk3, n1d); } \
    part[p][wv][l] = make_float2((n0a + n0b) + (n0c + n0d), (n1a + n1b) + (n1c + n1d)); \
    BARRIER_LG(); \
    float2 q0 = part[p][0][l], q1 = part[p][1][l], q2 = part[p][2][l], q3 = part[p][3][l]; \
    float s0 = (q0.x + q1.x) + (q2.x + q3.x); \
    float s1 = (q0.y + q1.y) + (q2.y + q3.y); \
    if ((((CIDX) & 1) == 0) && (CIDX) >= 2) { \
        s0 *= mrApply; s1 *= mrApply; \
        S -= __logf(mrApply); \
    } \
    g0 = s0; g1 = s1; \
    *(float2*)&gl[p ^ 1][2 * l] = make_float2(g0, g1); \
    if (((CIDX) & 1) == 0) { \
        float mx = wave_max_dpp(fmaxf(g0, g1));   /* off critical path */ \
        mrApply = __builtin_amdgcn_rcpf(fmaxf(mx, 1e-35f)); \
    } \
    p ^= 1; \
}

    if (nc > 0) {
        LOADCH(cwA, 0);
        if (nc > 1) LOADCH(cwB, 1);
        if (nc > 2) LOADCH(cwC, 2);
        int c = 0;
        while (true) {
            CSTEP(cwA, cwD, c); ++c; if (c >= nc) break;
            CSTEP(cwB, cwA, c); ++c; if (c >= nc) break;
            CSTEP(cwC, cwB, c); ++c; if (c >= nc) break;
            CSTEP(cwD, cwC, c); ++c; if (c >= nc) break;
        }
    }
#undef LOADCH
#undef CSTEP

    // ---- final: out[b] = S + log(sum_j gamma[j] * e[d-1][j])
    float e0 = e[((size_t)b * T_ + (d - 1)) * N_ + 2 * l];
    float e1 = e[((size_t)b * T_ + (d - 1)) * N_ + 2 * l + 1];
    float sv = g0 * e0 + g1 * e1;
    #pragma unroll
    for (int of = 1; of < 64; of <<= 1) sv += __shfl_xor(sv, of);
    if (tid == 0) out[b] = S + logf(sv);
}

extern "C" void kernel_launch(void* const* d_in, const int* in_sizes, int n_in,
                              void* d_out, int out_size, void* d_ws, size_t ws_size,
                              hipStream_t stream) {
    const float* obs   = (const float*)d_in[0];   // [B,T,K]
    const int*   dur   = (const int*)  d_in[1];   // [B]
    const float* trans = (const float*)d_in[2];   // [T,B,N,N]
    const float* sp    = (const float*)d_in[3];   // [B,N]
    const float* W     = (const float*)d_in[4];   // [K,N]
    const float* bias  = (const float*)d_in[5];   // [N]
    float* out = (float*)d_out;

    float* e = (float*)d_ws;                                   // 1 MB
    uint32_t* gout = (uint32_t*)((char*)d_ws + (size_t)B_ * T_ * N_ * 4);  // 8 MB

    hipLaunchKernelGGL(k_emit,  dim3(B_ * T_),  dim3(128), 0, stream, obs, dur, W, bias, e);
    hipLaunchKernelGGL(k_chunk, dim3(B_ * NCH), dim3(512), 0, stream, trans, dur, e, gout);
    hipLaunchKernelGGL(k_comb,  dim3(B_),       dim3(256), 0, stream, gout, dur, sp, e, out);
}